// Round 20
// baseline (428.879 us; speedup 1.0000x reference)
//
#include <hip/hip_runtime.h>

// SignSemanticsAggregator on MI355X (gfx950), round 20.
// E = sp + 32*sn (i8); E@E digits: M_same=(acc&31)+(acc>>10), M_diff=(acc>>5)&31.
// Round-20: 128x256 tiles, 8 waves each 64x64 (square per-wave tile ->
// 8 ds_read + 16 MFMA per phase = 0.5 reads/MFMA, LDS traffic -45% vs R18),
// BK=64, 2x24KB LDS dbuf -> 3 blocks/CU (24 waves/CU). Drain schedule and
// both-sides swizzle verbatim from the champion. 272 heavy tiles (i<=2j+1)
// + guarded mirror-xor tails.

#define NN 4096
#define NW 128
#define MASK_BYTES ((size_t)NN * NW * 4)     // 2 MiB per mask
#define MASK_WORDS ((size_t)NN * NW)

typedef unsigned int u32;
typedef __attribute__((ext_vector_type(4))) int int4v;
typedef __attribute__((ext_vector_type(4))) float f32x4;

__device__ __forceinline__ void gload_lds16(const char* g, char* l) {
    __builtin_amdgcn_global_load_lds(
        (const __attribute__((address_space(1))) void*)g,
        (__attribute__((address_space(3))) void*)l, 16, 0, 0);
}

// ---------------- preprocessing ----------------

__global__ void zero_ws(int4v* __restrict__ p) {
    p[blockIdx.x * 256 + threadIdx.x] = int4v{0, 0, 0, 0};   // 8 MiB
}

__global__ void scatter_all(const int* __restrict__ e0, const int* __restrict__ e1,
                            const int* __restrict__ e2, const int* __restrict__ e3,
                            int E0, int E1, int E2, int E3,
                            u32* __restrict__ ws) {
    int i = blockIdx.x * blockDim.x + threadIdx.x;
    u32* Pt = ws + 0 * MASK_WORDS;
    u32* P1 = ws + 1 * MASK_WORDS;
    u32* Nt = ws + 2 * MASK_WORDS;
    u32* N1 = ws + 3 * MASK_WORDS;
    if (i < E0) { int r = e0[i], c = e0[i + E0];
        atomicOr(&Pt[r * NW + (c >> 5)], 1u << (c & 31)); }
    if (i < E1) { int r = e1[i], c = e1[i + E1];
        atomicOr(&P1[r * NW + (c >> 5)], 1u << (c & 31)); }
    if (i < E2) { int r = e2[i], c = e2[i + E2];
        atomicOr(&Nt[r * NW + (c >> 5)], 1u << (c & 31)); }
    if (i < E3) { int r = e3[i], c = e3[i + E3];
        atomicOr(&N1[r * NW + (c >> 5)], 1u << (c & 31)); }
}

// Expand 16 mask bits (sp, sn) -> 16 i8 of E = sp + 32*sn.
__device__ __forceinline__ int4v expand_e(u32 sp, u32 sn) {
    int4v E;
    #pragma unroll
    for (int i = 0; i < 4; i++) {
        u32 p = (((sp >> (4 * i)) & 0xFu) * 0x00204081u) & 0x01010101u;
        u32 n = (((sn >> (4 * i)) & 0xFu) * 0x00204081u) & 0x01010101u;
        E[i] = (int)(p | (n << 5));
    }
    return E;
}

// Blocks [0,2048): E row-wise from P1/N1. Blocks [2048,4096): ET via in-wave
// ballot bit-transpose. Pos-priority and diagonal clearing in both halves.
__global__ void build_both(const u32* __restrict__ masks,
                           char* __restrict__ E, char* __restrict__ ET) {
    const u32* P  = masks + 1 * MASK_WORDS;
    const u32* Nm = masks + 3 * MASK_WORDS;
    if (blockIdx.x < 2048) {
        int w = blockIdx.x * 256 + threadIdx.x;      // word index a*128 + col
        u32 p = P[w];
        u32 n = Nm[w] & ~p;
        int a = w >> 7, col = w & 127;
        if ((a >> 5) == col) {
            u32 db = 1u << (a & 31);
            p &= ~db; n &= ~db;
        }
        char* dst = E + (size_t)a * NN + col * 32;
        *reinterpret_cast<int4v*>(dst)      = expand_e(p & 0xFFFFu, n & 0xFFFFu);
        *reinterpret_cast<int4v*>(dst + 16) = expand_e(p >> 16, n >> 16);
    } else {
        int gw = (blockIdx.x - 2048) * 4 + (threadIdx.x >> 6);  // 8192 waves
        int lane = threadIdx.x & 63;
        int ab = gw >> 7;        // 64-row block of a
        int wc = gw & 127;       // word column (c-block of 32)
        u32 pw = P[(ab * 64 + lane) * NW + wc];
        u32 nw = Nm[(ab * 64 + lane) * NW + wc];
        u32 myp = 0, myn = 0;
        #pragma unroll
        for (int j = 0; j < 32; j++) {
            unsigned long long bp = __ballot((pw >> j) & 1u);
            unsigned long long bn = __ballot((nw >> j) & 1u);
            if ((lane & 31) == j) {
                myp = (lane < 32) ? (u32)bp : (u32)(bp >> 32);
                myn = (lane < 32) ? (u32)bn : (u32)(bn >> 32);
            }
        }
        u32 p = myp;
        u32 n = myn & ~p;
        int c = wc * 32 + (lane & 31);
        int abase = ab * 64 + (lane >> 5) * 32;
        if (c >= abase && c < abase + 32) {          // clear diagonal a == c
            u32 db = 1u << (c - abase);
            p &= ~db; n &= ~db;
        }
        char* dst = ET + (size_t)c * NN + abase;
        *reinterpret_cast<int4v*>(dst)      = expand_e(p & 0xFFFFu, n & 0xFFFFu);
        *reinterpret_cast<int4v*>(dst + 16) = expand_e(p >> 16, n >> 16);
    }
}

// ---------------- fused GEMM + epilogue ----------------
// Grid = 272 tiles of 128(rows a) x 256(cols c), i <= 2j+1 (covers upper tri).
// BK=64, 64 phases, 2 x 24 KB dbuf (48 KB -> 3 blocks/CU), 8 waves of 64x64.
// Guarded mirror-xor after epilogue.
__global__ __launch_bounds__(512, 6) void gemm_ep(
    const char* __restrict__ E, const char* __restrict__ ET,
    const u32* __restrict__ Pt, const u32* __restrict__ P1,
    const u32* __restrict__ Nt, const u32* __restrict__ N1,
    float* __restrict__ out)
{
    const int tid = threadIdx.x;
    const size_t plane = (size_t)NN * NN;

    // bijective XCD swizzle over 272 blocks (272 = 8 * 34)
    const int id = ((int)blockIdx.x & 7) * 34 + ((int)blockIdx.x >> 3);
    // column-tile j has tiles i in [0, 2j+2); cum(j) = j*(j+1)
    int j = (int)((sqrtf(4.0f * (float)id + 1.0f) - 1.0f) * 0.5f);
    if (j > 15) j = 15;
    while (j > 0 && j * (j + 1) > id) --j;
    while ((j + 1) * (j + 2) <= id) ++j;
    const int i = id - j * (j + 1);          // 0 .. 2j+1
    const int a0 = i << 7, c0 = j << 8;

    // [buf][ A: 0..8191 (128 rows x 64B) | B: 8192..24575 (256 rows) ], 48 KB
    __shared__ char LB[2][24576];

    const int wave = tid >> 6, lane = tid & 63;
    const int wr = (wave >> 2) * 64;         // 2 wave-rows of 64
    const int wcol = (wave & 3) * 64;        // 4 wave-cols of 64
    const int lr = lane & 15, lg = lane >> 4;

    // Staging: thread covers row tid>>2, chunk tid&3 of a 64-B K-row.
    // Source chunk = (tid&3) ^ ((row>>1)&3); (row>>1)&3 == (tid>>3)&3.
    const int soff = (((tid & 3) ^ ((tid >> 3) & 3)) << 4);
    const char* gA  = E  + (size_t)(a0 + (tid >> 2)) * NN + soff;
    const char* gB0 = ET + (size_t)(c0 + (tid >> 2)) * NN + soff;
    const char* gB1 = gB0 + (size_t)128 * NN;
    const int t16 = tid * 16;

    int4v acc[4][4];
    int4v zero = {0, 0, 0, 0};
    #pragma unroll
    for (int m = 0; m < 4; m++)
        #pragma unroll
        for (int n = 0; n < 4; n++) acc[m][n] = zero;

    #define STAGE(b, p)                                           \
        do {                                                      \
            const int koff = (p) * 64;                            \
            gload_lds16(gA  + koff, &LB[b][t16]);                 \
            gload_lds16(gB0 + koff, &LB[b][8192 + t16]);          \
            gload_lds16(gB1 + koff, &LB[b][16384 + t16]);         \
        } while (0)

    #define COMPUTE(b)                                                         \
        do {                                                                   \
            int4v bf[4];                                                       \
            _Pragma("unroll")                                                  \
            for (int n = 0; n < 4; n++) {                                      \
                int rowb = wcol + n * 16 + lr;                                 \
                bf[n] = *reinterpret_cast<const int4v*>(&LB[b][                \
                    8192 + rowb * 64 + ((lg ^ ((rowb >> 1) & 3)) << 4)]);      \
            }                                                                  \
            __builtin_amdgcn_s_setprio(1);                                     \
            _Pragma("unroll")                                                  \
            for (int m = 0; m < 4; m++) {                                      \
                int rowa = wr + m * 16 + lr;                                   \
                int4v af = *reinterpret_cast<const int4v*>(&LB[b][             \
                    rowa * 64 + ((lg ^ ((rowa >> 1) & 3)) << 4)]);             \
                _Pragma("unroll")                                              \
                for (int n = 0; n < 4; n++)                                    \
                    acc[m][n] = __builtin_amdgcn_mfma_i32_16x16x64_i8(         \
                        af, bf[n], acc[m][n], 0, 0, 0);                        \
            }                                                                  \
            __builtin_amdgcn_s_setprio(0);                                     \
        } while (0)

    // prologue: stage phase 0, drain (3 staging loads)
    STAGE(0, 0);
    asm volatile("s_waitcnt vmcnt(0)" ::: "memory");
    __builtin_amdgcn_s_barrier();

    int cur = 0;
    for (int p = 0; p < 63; ++p) {
        STAGE(cur ^ 1, p + 1);               // 3 loads for next phase
        COMPUTE(cur);                        // 8 ds_read + 16 MFMA
        asm volatile("s_waitcnt vmcnt(0)" ::: "memory");   // next buf staged
        __builtin_amdgcn_s_barrier();
        cur ^= 1;
    }
    COMPUTE(cur);                            // p = 63
    #undef STAGE
    #undef COMPUTE

    // ---- fused epilogue: C/D layout col=lane&15, row=(lane>>4)*4+q ----
    #pragma unroll
    for (int m = 0; m < 4; m++) {
        #pragma unroll
        for (int n = 0; n < 4; n++) {
            #pragma unroll
            for (int q = 0; q < 4; q++) {
                int a = a0 + wr + m * 16 + lg * 4 + q;
                int c = c0 + wcol + n * 16 + lr;
                int widx = a * NW + (c >> 5);
                int bit = c & 31;
                u32 p1 = (P1[widx] >> bit) & 1u;
                u32 n1 = (N1[widx] >> bit) & 1u;
                u32 pt = (Pt[widx] >> bit) & 1u;
                u32 nt = (Nt[widx] >> bit) & 1u;
                int av = acc[m][n][q];
                int Ms = (av & 31) + (av >> 10);     // d0 + d2
                int Md = (av >> 5) & 31;             // d1
                int o0 = (int)(pt ^ p1) + ((a < c && !p1) ? Ms : 0);
                int o1 = (int)(nt ^ n1) + ((a < c && !n1) ? Md : 0);
                size_t oi = (size_t)a * NN + c;
                out[oi] = (float)o0;
                out[plane + oi] = (float)o1;
            }
        }
    }

    // ---- mirror xor: rows [c0,c0+256) x cols [a0,a0+128), skipping cells
    // covered by some heavy tile's epilogue ((R>>7) <= 2*(C>>8)+1). ----
    {
        #pragma unroll 4
        for (int pass = 0; pass < 16; ++pass) {
            int e = pass * 2048 + tid * 4;       // element in 256x128 mirror
            int rr = e >> 7, cc = e & 127;
            int R = c0 + rr, C = a0 + cc;
            if ((R >> 7) <= 2 * (C >> 8) + 1) continue;   // epilogue-covered
            int widx = R * NW + (C >> 5);
            int sh = C & 31;
            u32 xp = (P1[widx] ^ Pt[widx]) >> sh;
            u32 xn = (N1[widx] ^ Nt[widx]) >> sh;
            f32x4 o0, o1;
            #pragma unroll
            for (int v = 0; v < 4; v++) {
                o0[v] = (float)((xp >> v) & 1u);
                o1[v] = (float)((xn >> v) & 1u);
            }
            size_t ob = (size_t)R * NN + C;
            *reinterpret_cast<f32x4*>(out + ob) = o0;
            *reinterpret_cast<f32x4*>(out + plane + ob) = o1;
        }
    }
}

extern "C" void kernel_launch(void* const* d_in, const int* in_sizes, int n_in,
                              void* d_out, int out_size, void* d_ws, size_t ws_size,
                              hipStream_t stream) {
    char* ws = (char*)d_ws;
    u32* masks = (u32*)ws;                    // Pt,P1,Nt,N1 (4 x 2 MiB)
    u32* Pt = masks + 0 * MASK_WORDS;
    u32* P1 = masks + 1 * MASK_WORDS;
    u32* Nt = masks + 2 * MASK_WORDS;
    u32* N1 = masks + 3 * MASK_WORDS;
    char* E  = ws + 4 * MASK_BYTES;           // 16 MiB, linear
    char* ET = E + (size_t)NN * NN;           // 16 MiB, linear
    // ws use: 8 MiB masks + 32 MiB E/ET = 40 MiB

    zero_ws<<<2048, 256, 0, stream>>>((int4v*)masks);   // 8 MiB, ~2 us

    // input order: A_pos_t, A_pos_tp1, A_neg_t, A_neg_tp1
    int E0 = in_sizes[0] / 2, E1 = in_sizes[1] / 2;
    int E2 = in_sizes[2] / 2, E3 = in_sizes[3] / 2;
    int Emax = max(max(E0, E1), max(E2, E3));
    scatter_all<<<(Emax + 255) / 256, 256, 0, stream>>>(
        (const int*)d_in[0], (const int*)d_in[1], (const int*)d_in[2],
        (const int*)d_in[3], E0, E1, E2, E3, masks);

    build_both<<<4096, 256, 0, stream>>>(masks, E, ET);

    gemm_ep<<<272, 512, 0, stream>>>(E, ET, Pt, P1, Nt, N1, (float*)d_out);
}

// Round 21
// 134.915 us; speedup vs baseline: 3.1789x; 3.1789x over previous
//
#include <hip/hip_runtime.h>

// SignSemanticsAggregator on MI355X (gfx950), round 21.
// E = sp + 32*sn (i8); E@E digits: M_same=(acc&31)+(acc>>10), M_diff=(acc>>5)&31.
// Round-21: R20 geometry (128x256 tiles, 8 waves each 64x64, BK=64,
// 2x24KB dbuf) with the launch_bounds spill bug fixed: (512,2) instead of
// (512,6). R20's VGPR cap of ~85 spilled the 64-reg accumulator to scratch
// (VGPR=40, WRITE 681MB, gemm 390us). Everything else identical.

#define NN 4096
#define NW 128
#define MASK_BYTES ((size_t)NN * NW * 4)     // 2 MiB per mask
#define MASK_WORDS ((size_t)NN * NW)

typedef unsigned int u32;
typedef __attribute__((ext_vector_type(4))) int int4v;
typedef __attribute__((ext_vector_type(4))) float f32x4;

__device__ __forceinline__ void gload_lds16(const char* g, char* l) {
    __builtin_amdgcn_global_load_lds(
        (const __attribute__((address_space(1))) void*)g,
        (__attribute__((address_space(3))) void*)l, 16, 0, 0);
}

// ---------------- preprocessing ----------------

__global__ void zero_ws(int4v* __restrict__ p) {
    p[blockIdx.x * 256 + threadIdx.x] = int4v{0, 0, 0, 0};   // 8 MiB
}

__global__ void scatter_all(const int* __restrict__ e0, const int* __restrict__ e1,
                            const int* __restrict__ e2, const int* __restrict__ e3,
                            int E0, int E1, int E2, int E3,
                            u32* __restrict__ ws) {
    int i = blockIdx.x * blockDim.x + threadIdx.x;
    u32* Pt = ws + 0 * MASK_WORDS;
    u32* P1 = ws + 1 * MASK_WORDS;
    u32* Nt = ws + 2 * MASK_WORDS;
    u32* N1 = ws + 3 * MASK_WORDS;
    if (i < E0) { int r = e0[i], c = e0[i + E0];
        atomicOr(&Pt[r * NW + (c >> 5)], 1u << (c & 31)); }
    if (i < E1) { int r = e1[i], c = e1[i + E1];
        atomicOr(&P1[r * NW + (c >> 5)], 1u << (c & 31)); }
    if (i < E2) { int r = e2[i], c = e2[i + E2];
        atomicOr(&Nt[r * NW + (c >> 5)], 1u << (c & 31)); }
    if (i < E3) { int r = e3[i], c = e3[i + E3];
        atomicOr(&N1[r * NW + (c >> 5)], 1u << (c & 31)); }
}

// Expand 16 mask bits (sp, sn) -> 16 i8 of E = sp + 32*sn.
__device__ __forceinline__ int4v expand_e(u32 sp, u32 sn) {
    int4v E;
    #pragma unroll
    for (int i = 0; i < 4; i++) {
        u32 p = (((sp >> (4 * i)) & 0xFu) * 0x00204081u) & 0x01010101u;
        u32 n = (((sn >> (4 * i)) & 0xFu) * 0x00204081u) & 0x01010101u;
        E[i] = (int)(p | (n << 5));
    }
    return E;
}

// Blocks [0,2048): E row-wise from P1/N1. Blocks [2048,4096): ET via in-wave
// ballot bit-transpose. Pos-priority and diagonal clearing in both halves.
__global__ void build_both(const u32* __restrict__ masks,
                           char* __restrict__ E, char* __restrict__ ET) {
    const u32* P  = masks + 1 * MASK_WORDS;
    const u32* Nm = masks + 3 * MASK_WORDS;
    if (blockIdx.x < 2048) {
        int w = blockIdx.x * 256 + threadIdx.x;      // word index a*128 + col
        u32 p = P[w];
        u32 n = Nm[w] & ~p;
        int a = w >> 7, col = w & 127;
        if ((a >> 5) == col) {
            u32 db = 1u << (a & 31);
            p &= ~db; n &= ~db;
        }
        char* dst = E + (size_t)a * NN + col * 32;
        *reinterpret_cast<int4v*>(dst)      = expand_e(p & 0xFFFFu, n & 0xFFFFu);
        *reinterpret_cast<int4v*>(dst + 16) = expand_e(p >> 16, n >> 16);
    } else {
        int gw = (blockIdx.x - 2048) * 4 + (threadIdx.x >> 6);  // 8192 waves
        int lane = threadIdx.x & 63;
        int ab = gw >> 7;        // 64-row block of a
        int wc = gw & 127;       // word column (c-block of 32)
        u32 pw = P[(ab * 64 + lane) * NW + wc];
        u32 nw = Nm[(ab * 64 + lane) * NW + wc];
        u32 myp = 0, myn = 0;
        #pragma unroll
        for (int j = 0; j < 32; j++) {
            unsigned long long bp = __ballot((pw >> j) & 1u);
            unsigned long long bn = __ballot((nw >> j) & 1u);
            if ((lane & 31) == j) {
                myp = (lane < 32) ? (u32)bp : (u32)(bp >> 32);
                myn = (lane < 32) ? (u32)bn : (u32)(bn >> 32);
            }
        }
        u32 p = myp;
        u32 n = myn & ~p;
        int c = wc * 32 + (lane & 31);
        int abase = ab * 64 + (lane >> 5) * 32;
        if (c >= abase && c < abase + 32) {          // clear diagonal a == c
            u32 db = 1u << (c - abase);
            p &= ~db; n &= ~db;
        }
        char* dst = ET + (size_t)c * NN + abase;
        *reinterpret_cast<int4v*>(dst)      = expand_e(p & 0xFFFFu, n & 0xFFFFu);
        *reinterpret_cast<int4v*>(dst + 16) = expand_e(p >> 16, n >> 16);
    }
}

// ---------------- fused GEMM + epilogue ----------------
// Grid = 272 tiles of 128(rows a) x 256(cols c), i <= 2j+1 (covers upper tri).
// BK=64, 64 phases, 2 x 24 KB dbuf, 8 waves of 64x64. Guarded mirror-xor
// after epilogue.
__global__ __launch_bounds__(512, 2) void gemm_ep(
    const char* __restrict__ E, const char* __restrict__ ET,
    const u32* __restrict__ Pt, const u32* __restrict__ P1,
    const u32* __restrict__ Nt, const u32* __restrict__ N1,
    float* __restrict__ out)
{
    const int tid = threadIdx.x;
    const size_t plane = (size_t)NN * NN;

    // bijective XCD swizzle over 272 blocks (272 = 8 * 34)
    const int id = ((int)blockIdx.x & 7) * 34 + ((int)blockIdx.x >> 3);
    // column-tile j has tiles i in [0, 2j+2); cum(j) = j*(j+1)
    int j = (int)((sqrtf(4.0f * (float)id + 1.0f) - 1.0f) * 0.5f);
    if (j > 15) j = 15;
    while (j > 0 && j * (j + 1) > id) --j;
    while ((j + 1) * (j + 2) <= id) ++j;
    const int i = id - j * (j + 1);          // 0 .. 2j+1
    const int a0 = i << 7, c0 = j << 8;

    // [buf][ A: 0..8191 (128 rows x 64B) | B: 8192..24575 (256 rows) ], 48 KB
    __shared__ char LB[2][24576];

    const int wave = tid >> 6, lane = tid & 63;
    const int wr = (wave >> 2) * 64;         // 2 wave-rows of 64
    const int wcol = (wave & 3) * 64;        // 4 wave-cols of 64
    const int lr = lane & 15, lg = lane >> 4;

    // Staging: thread covers row tid>>2, chunk tid&3 of a 64-B K-row.
    // Source chunk = (tid&3) ^ ((row>>1)&3); (row>>1)&3 == (tid>>3)&3.
    const int soff = (((tid & 3) ^ ((tid >> 3) & 3)) << 4);
    const char* gA  = E  + (size_t)(a0 + (tid >> 2)) * NN + soff;
    const char* gB0 = ET + (size_t)(c0 + (tid >> 2)) * NN + soff;
    const char* gB1 = gB0 + (size_t)128 * NN;
    const int t16 = tid * 16;

    int4v acc[4][4];
    int4v zero = {0, 0, 0, 0};
    #pragma unroll
    for (int m = 0; m < 4; m++)
        #pragma unroll
        for (int n = 0; n < 4; n++) acc[m][n] = zero;

    #define STAGE(b, p)                                           \
        do {                                                      \
            const int koff = (p) * 64;                            \
            gload_lds16(gA  + koff, &LB[b][t16]);                 \
            gload_lds16(gB0 + koff, &LB[b][8192 + t16]);          \
            gload_lds16(gB1 + koff, &LB[b][16384 + t16]);         \
        } while (0)

    #define COMPUTE(b)                                                         \
        do {                                                                   \
            int4v bf[4];                                                       \
            _Pragma("unroll")                                                  \
            for (int n = 0; n < 4; n++) {                                      \
                int rowb = wcol + n * 16 + lr;                                 \
                bf[n] = *reinterpret_cast<const int4v*>(&LB[b][                \
                    8192 + rowb * 64 + ((lg ^ ((rowb >> 1) & 3)) << 4)]);      \
            }                                                                  \
            __builtin_amdgcn_s_setprio(1);                                     \
            _Pragma("unroll")                                                  \
            for (int m = 0; m < 4; m++) {                                      \
                int rowa = wr + m * 16 + lr;                                   \
                int4v af = *reinterpret_cast<const int4v*>(&LB[b][             \
                    rowa * 64 + ((lg ^ ((rowa >> 1) & 3)) << 4)]);             \
                _Pragma("unroll")                                              \
                for (int n = 0; n < 4; n++)                                    \
                    acc[m][n] = __builtin_amdgcn_mfma_i32_16x16x64_i8(         \
                        af, bf[n], acc[m][n], 0, 0, 0);                        \
            }                                                                  \
            __builtin_amdgcn_s_setprio(0);                                     \
        } while (0)

    // prologue: stage phase 0, drain (3 staging loads)
    STAGE(0, 0);
    asm volatile("s_waitcnt vmcnt(0)" ::: "memory");
    __builtin_amdgcn_s_barrier();

    int cur = 0;
    for (int p = 0; p < 63; ++p) {
        STAGE(cur ^ 1, p + 1);               // 3 loads for next phase
        COMPUTE(cur);                        // 8 ds_read + 16 MFMA
        asm volatile("s_waitcnt vmcnt(0)" ::: "memory");   // next buf staged
        __builtin_amdgcn_s_barrier();
        cur ^= 1;
    }
    COMPUTE(cur);                            // p = 63
    #undef STAGE
    #undef COMPUTE

    // ---- fused epilogue: C/D layout col=lane&15, row=(lane>>4)*4+q ----
    #pragma unroll
    for (int m = 0; m < 4; m++) {
        #pragma unroll
        for (int n = 0; n < 4; n++) {
            #pragma unroll
            for (int q = 0; q < 4; q++) {
                int a = a0 + wr + m * 16 + lg * 4 + q;
                int c = c0 + wcol + n * 16 + lr;
                int widx = a * NW + (c >> 5);
                int bit = c & 31;
                u32 p1 = (P1[widx] >> bit) & 1u;
                u32 n1 = (N1[widx] >> bit) & 1u;
                u32 pt = (Pt[widx] >> bit) & 1u;
                u32 nt = (Nt[widx] >> bit) & 1u;
                int av = acc[m][n][q];
                int Ms = (av & 31) + (av >> 10);     // d0 + d2
                int Md = (av >> 5) & 31;             // d1
                int o0 = (int)(pt ^ p1) + ((a < c && !p1) ? Ms : 0);
                int o1 = (int)(nt ^ n1) + ((a < c && !n1) ? Md : 0);
                size_t oi = (size_t)a * NN + c;
                out[oi] = (float)o0;
                out[plane + oi] = (float)o1;
            }
        }
    }

    // ---- mirror xor: rows [c0,c0+256) x cols [a0,a0+128), skipping cells
    // covered by some heavy tile's epilogue ((R>>7) <= 2*(C>>8)+1). ----
    {
        #pragma unroll 4
        for (int pass = 0; pass < 16; ++pass) {
            int e = pass * 2048 + tid * 4;       // element in 256x128 mirror
            int rr = e >> 7, cc = e & 127;
            int R = c0 + rr, C = a0 + cc;
            if ((R >> 7) <= 2 * (C >> 8) + 1) continue;   // epilogue-covered
            int widx = R * NW + (C >> 5);
            int sh = C & 31;
            u32 xp = (P1[widx] ^ Pt[widx]) >> sh;
            u32 xn = (N1[widx] ^ Nt[widx]) >> sh;
            f32x4 o0, o1;
            #pragma unroll
            for (int v = 0; v < 4; v++) {
                o0[v] = (float)((xp >> v) & 1u);
                o1[v] = (float)((xn >> v) & 1u);
            }
            size_t ob = (size_t)R * NN + C;
            *reinterpret_cast<f32x4*>(out + ob) = o0;
            *reinterpret_cast<f32x4*>(out + plane + ob) = o1;
        }
    }
}

extern "C" void kernel_launch(void* const* d_in, const int* in_sizes, int n_in,
                              void* d_out, int out_size, void* d_ws, size_t ws_size,
                              hipStream_t stream) {
    char* ws = (char*)d_ws;
    u32* masks = (u32*)ws;                    // Pt,P1,Nt,N1 (4 x 2 MiB)
    u32* Pt = masks + 0 * MASK_WORDS;
    u32* P1 = masks + 1 * MASK_WORDS;
    u32* Nt = masks + 2 * MASK_WORDS;
    u32* N1 = masks + 3 * MASK_WORDS;
    char* E  = ws + 4 * MASK_BYTES;           // 16 MiB, linear
    char* ET = E + (size_t)NN * NN;           // 16 MiB, linear
    // ws use: 8 MiB masks + 32 MiB E/ET = 40 MiB

    zero_ws<<<2048, 256, 0, stream>>>((int4v*)masks);   // 8 MiB, ~2 us

    // input order: A_pos_t, A_pos_tp1, A_neg_t, A_neg_tp1
    int E0 = in_sizes[0] / 2, E1 = in_sizes[1] / 2;
    int E2 = in_sizes[2] / 2, E3 = in_sizes[3] / 2;
    int Emax = max(max(E0, E1), max(E2, E3));
    scatter_all<<<(Emax + 255) / 256, 256, 0, stream>>>(
        (const int*)d_in[0], (const int*)d_in[1], (const int*)d_in[2],
        (const int*)d_in[3], E0, E1, E2, E3, masks);

    build_both<<<4096, 256, 0, stream>>>(masks, E, ET);

    gemm_ep<<<272, 512, 0, stream>>>(E, ET, Pt, P1, Nt, N1, (float*)d_out);
}

// Round 22
// 128.099 us; speedup vs baseline: 3.3480x; 1.0532x over previous
//
#include <hip/hip_runtime.h>

// SignSemanticsAggregator on MI355X (gfx950) — FINAL (revert to round-18 champion).
// E = sp + 32*sn (i8); E@E digits: M_same=(acc&31)+(acc>>10), M_diff=(acc>>5)&31.
// Champion structure: BK=128, 32 phases, 2x32KB LDS dbuf, all-DMA staging
// (global_load_lds w=16) with both-sides XOR swizzle (slot ^ row&7),
// 512 thr / 8 waves of 32x64, drain-per-phase schedule, 528 upper-tri
// 128x128 tiles w/ XCD swizzle, mirror-xor fire-and-forget tail.
// History: 806 -> 128.4 us over 18 passing rounds; absmax 0 throughout.

#define NN 4096
#define NW 128
#define MASK_BYTES ((size_t)NN * NW * 4)     // 2 MiB per mask
#define MASK_WORDS ((size_t)NN * NW)

typedef unsigned int u32;
typedef __attribute__((ext_vector_type(4))) int int4v;
typedef __attribute__((ext_vector_type(4))) float f32x4;

__device__ __forceinline__ void gload_lds16(const char* g, char* l) {
    __builtin_amdgcn_global_load_lds(
        (const __attribute__((address_space(1))) void*)g,
        (__attribute__((address_space(3))) void*)l, 16, 0, 0);
}

// ---------------- preprocessing ----------------

__global__ void zero_ws(int4v* __restrict__ p) {
    p[blockIdx.x * 256 + threadIdx.x] = int4v{0, 0, 0, 0};   // 8 MiB
}

__global__ void scatter_all(const int* __restrict__ e0, const int* __restrict__ e1,
                            const int* __restrict__ e2, const int* __restrict__ e3,
                            int E0, int E1, int E2, int E3,
                            u32* __restrict__ ws) {
    int i = blockIdx.x * blockDim.x + threadIdx.x;
    u32* Pt = ws + 0 * MASK_WORDS;
    u32* P1 = ws + 1 * MASK_WORDS;
    u32* Nt = ws + 2 * MASK_WORDS;
    u32* N1 = ws + 3 * MASK_WORDS;
    if (i < E0) { int r = e0[i], c = e0[i + E0];
        atomicOr(&Pt[r * NW + (c >> 5)], 1u << (c & 31)); }
    if (i < E1) { int r = e1[i], c = e1[i + E1];
        atomicOr(&P1[r * NW + (c >> 5)], 1u << (c & 31)); }
    if (i < E2) { int r = e2[i], c = e2[i + E2];
        atomicOr(&Nt[r * NW + (c >> 5)], 1u << (c & 31)); }
    if (i < E3) { int r = e3[i], c = e3[i + E3];
        atomicOr(&N1[r * NW + (c >> 5)], 1u << (c & 31)); }
}

// Expand 16 mask bits (sp, sn) -> 16 i8 of E = sp + 32*sn.
__device__ __forceinline__ int4v expand_e(u32 sp, u32 sn) {
    int4v E;
    #pragma unroll
    for (int i = 0; i < 4; i++) {
        u32 p = (((sp >> (4 * i)) & 0xFu) * 0x00204081u) & 0x01010101u;
        u32 n = (((sn >> (4 * i)) & 0xFu) * 0x00204081u) & 0x01010101u;
        E[i] = (int)(p | (n << 5));
    }
    return E;
}

// Blocks [0,2048): E row-wise from P1/N1. Blocks [2048,4096): ET via in-wave
// ballot bit-transpose. Pos-priority and diagonal clearing in both halves.
__global__ void build_both(const u32* __restrict__ masks,
                           char* __restrict__ E, char* __restrict__ ET) {
    const u32* P  = masks + 1 * MASK_WORDS;
    const u32* Nm = masks + 3 * MASK_WORDS;
    if (blockIdx.x < 2048) {
        int w = blockIdx.x * 256 + threadIdx.x;      // word index a*128 + col
        u32 p = P[w];
        u32 n = Nm[w] & ~p;
        int a = w >> 7, col = w & 127;
        if ((a >> 5) == col) {
            u32 db = 1u << (a & 31);
            p &= ~db; n &= ~db;
        }
        char* dst = E + (size_t)a * NN + col * 32;
        *reinterpret_cast<int4v*>(dst)      = expand_e(p & 0xFFFFu, n & 0xFFFFu);
        *reinterpret_cast<int4v*>(dst + 16) = expand_e(p >> 16, n >> 16);
    } else {
        int gw = (blockIdx.x - 2048) * 4 + (threadIdx.x >> 6);  // 8192 waves
        int lane = threadIdx.x & 63;
        int ab = gw >> 7;        // 64-row block of a
        int wc = gw & 127;       // word column (c-block of 32)
        u32 pw = P[(ab * 64 + lane) * NW + wc];
        u32 nw = Nm[(ab * 64 + lane) * NW + wc];
        u32 myp = 0, myn = 0;
        #pragma unroll
        for (int j = 0; j < 32; j++) {
            unsigned long long bp = __ballot((pw >> j) & 1u);
            unsigned long long bn = __ballot((nw >> j) & 1u);
            if ((lane & 31) == j) {
                myp = (lane < 32) ? (u32)bp : (u32)(bp >> 32);
                myn = (lane < 32) ? (u32)bn : (u32)(bn >> 32);
            }
        }
        u32 p = myp;
        u32 n = myn & ~p;
        int c = wc * 32 + (lane & 31);
        int abase = ab * 64 + (lane >> 5) * 32;
        if (c >= abase && c < abase + 32) {          // clear diagonal a == c
            u32 db = 1u << (c - abase);
            p &= ~db; n &= ~db;
        }
        char* dst = ET + (size_t)c * NN + abase;
        *reinterpret_cast<int4v*>(dst)      = expand_e(p & 0xFFFFu, n & 0xFFFFu);
        *reinterpret_cast<int4v*>(dst + 16) = expand_e(p >> 16, n >> 16);
    }
}

// ---------------- fused GEMM + epilogue ----------------
// Grid = 528 upper-tri 128x128 tiles. BK=128, 32 K-phases, 2 x 32 KB LDS
// buffers, stage-ahead-1 drain. 8 waves of 32x64. Mirror-xor after epilogue.
__global__ __launch_bounds__(512, 4) void gemm_ep(
    const char* __restrict__ E, const char* __restrict__ ET,
    const u32* __restrict__ Pt, const u32* __restrict__ P1,
    const u32* __restrict__ Nt, const u32* __restrict__ N1,
    float* __restrict__ out)
{
    const int tid = threadIdx.x;
    const size_t plane = (size_t)NN * NN;

    // triangular tile map with bijective XCD swizzle (528 = 8 * 66)
    int s_ = ((int)blockIdx.x & 7) * 66 + ((int)blockIdx.x >> 3);
    int by = (int)((65.0f - sqrtf(4225.0f - 8.0f * (float)s_)) * 0.5f);
    if (by > 31) by = 31;
    while (by > 0 && 32 * by - (by * (by - 1)) / 2 > s_) --by;
    while (32 * (by + 1) - ((by + 1) * by) / 2 <= s_) ++by;
    int bx = by + s_ - (32 * by - (by * (by - 1)) / 2);
    const int a0 = by << 7, c0 = bx << 7;

    __shared__ char LB[2][2][16384];   // [buf][A/B][row*128 + slot*16], 64 KB

    const int wave = tid >> 6, lane = tid & 63;
    const int wr = (wave >> 1) * 32, wcol = (wave & 1) * 64;
    const int lr = lane & 15, lg = lane >> 4;

    // Staging (512 threads): instr i covers LDS [i*8192 + tid*16] =
    // row (64i + tid>>3), slot (tid&7). Source chunk = slot ^ (row&7).
    const int srow = tid >> 3;               // 0..63
    const int sslot = tid & 7;
    const int soff = ((sslot ^ (srow & 7)) << 4);
    const char* gA0 = E  + (size_t)(a0 + srow)      * NN + soff;
    const char* gA1 = E  + (size_t)(a0 + 64 + srow) * NN + soff;
    const char* gB0 = ET + (size_t)(c0 + srow)      * NN + soff;
    const char* gB1 = ET + (size_t)(c0 + 64 + srow) * NN + soff;
    const int t16 = tid * 16;

    int4v acc[2][4];
    int4v zero = {0, 0, 0, 0};
    #pragma unroll
    for (int m = 0; m < 2; m++)
        #pragma unroll
        for (int n = 0; n < 4; n++) acc[m][n] = zero;

    #define STAGE(b, p)                                           \
        do {                                                      \
            const int koff = (p) * 128;                           \
            gload_lds16(gA0 + koff, &LB[b][0][t16]);              \
            gload_lds16(gA1 + koff, &LB[b][0][8192 + t16]);       \
            gload_lds16(gB0 + koff, &LB[b][1][t16]);              \
            gload_lds16(gB1 + koff, &LB[b][1][8192 + t16]);       \
        } while (0)

    #define COMPUTE(b)                                                          \
        do {                                                                    \
            _Pragma("unroll")                                                   \
            for (int ks = 0; ks < 2; ks++) {                                    \
                int4v bf[4];                                                    \
                _Pragma("unroll")                                               \
                for (int n = 0; n < 4; n++) {                                   \
                    int rowb = wcol + n * 16 + lr;                              \
                    bf[n] = *reinterpret_cast<const int4v*>(&LB[b][1][          \
                        rowb * 128 + (((ks * 4 + lg) ^ (rowb & 7)) << 4)]);     \
                }                                                               \
                __builtin_amdgcn_s_setprio(1);                                  \
                _Pragma("unroll")                                               \
                for (int m = 0; m < 2; m++) {                                   \
                    int rowa = wr + m * 16 + lr;                                \
                    int4v af = *reinterpret_cast<const int4v*>(&LB[b][0][       \
                        rowa * 128 + (((ks * 4 + lg) ^ (rowa & 7)) << 4)]);     \
                    _Pragma("unroll")                                           \
                    for (int n = 0; n < 4; n++)                                 \
                        acc[m][n] = __builtin_amdgcn_mfma_i32_16x16x64_i8(      \
                            af, bf[n], acc[m][n], 0, 0, 0);                     \
                }                                                               \
                __builtin_amdgcn_s_setprio(0);                                  \
            }                                                                   \
        } while (0)

    // prologue: stage phase 0, drain (only 4 staging loads)
    STAGE(0, 0);
    asm volatile("s_waitcnt vmcnt(0)" ::: "memory");
    __builtin_amdgcn_s_barrier();

    int cur = 0;
    for (int p = 0; p < 31; ++p) {
        STAGE(cur ^ 1, p + 1);               // 4 loads for next phase
        COMPUTE(cur);                        // 12 ds_read + 16 MFMA
        asm volatile("s_waitcnt vmcnt(0)" ::: "memory");   // next buf staged
        __builtin_amdgcn_s_barrier();
        cur ^= 1;
    }
    COMPUTE(cur);                            // p = 31
    #undef STAGE
    #undef COMPUTE

    // ---- fused epilogue: C/D layout col=lane&15, row=(lane>>4)*4+q ----
    #pragma unroll
    for (int m = 0; m < 2; m++) {
        #pragma unroll
        for (int n = 0; n < 4; n++) {
            #pragma unroll
            for (int q = 0; q < 4; q++) {
                int a = a0 + wr + m * 16 + lg * 4 + q;
                int c = c0 + wcol + n * 16 + lr;
                int widx = a * NW + (c >> 5);
                int bit = c & 31;
                u32 p1 = (P1[widx] >> bit) & 1u;
                u32 n1 = (N1[widx] >> bit) & 1u;
                u32 pt = (Pt[widx] >> bit) & 1u;
                u32 nt = (Nt[widx] >> bit) & 1u;
                int av = acc[m][n][q];
                int Ms = (av & 31) + (av >> 10);     // d0 + d2
                int Md = (av >> 5) & 31;             // d1
                int o0 = (int)(pt ^ p1) + ((a < c && !p1) ? Ms : 0);
                int o1 = (int)(nt ^ n1) + ((a < c && !n1) ? Md : 0);
                size_t oi = (size_t)a * NN + c;
                out[oi] = (float)o0;
                out[plane + oi] = (float)o1;
            }
        }
    }

    // ---- mirror tile xor (strictly-lower mirror), fire-and-forget tail ----
    if (by != bx) {
        #pragma unroll 4
        for (int pass = 0; pass < 8; ++pass) {
            int e = pass * 2048 + tid * 4;       // element in 128x128 tile
            int r = e >> 7, cc = e & 127;
            int widx = (c0 + r) * NW + ((a0 + cc) >> 5);
            int sh = cc & 31;
            u32 xp = (P1[widx] ^ Pt[widx]) >> sh;
            u32 xn = (N1[widx] ^ Nt[widx]) >> sh;
            f32x4 o0, o1;
            #pragma unroll
            for (int i = 0; i < 4; i++) {
                o0[i] = (float)((xp >> i) & 1u);
                o1[i] = (float)((xn >> i) & 1u);
            }
            size_t ob = (size_t)(c0 + r) * NN + a0 + cc;
            *reinterpret_cast<f32x4*>(out + ob) = o0;
            *reinterpret_cast<f32x4*>(out + plane + ob) = o1;
        }
    }
}

extern "C" void kernel_launch(void* const* d_in, const int* in_sizes, int n_in,
                              void* d_out, int out_size, void* d_ws, size_t ws_size,
                              hipStream_t stream) {
    char* ws = (char*)d_ws;
    u32* masks = (u32*)ws;                    // Pt,P1,Nt,N1 (4 x 2 MiB)
    u32* Pt = masks + 0 * MASK_WORDS;
    u32* P1 = masks + 1 * MASK_WORDS;
    u32* Nt = masks + 2 * MASK_WORDS;
    u32* N1 = masks + 3 * MASK_WORDS;
    char* E  = ws + 4 * MASK_BYTES;           // 16 MiB, linear
    char* ET = E + (size_t)NN * NN;           // 16 MiB, linear
    // ws use: 8 MiB masks + 32 MiB E/ET = 40 MiB

    zero_ws<<<2048, 256, 0, stream>>>((int4v*)masks);   // 8 MiB, ~2 us

    // input order: A_pos_t, A_pos_tp1, A_neg_t, A_neg_tp1
    int E0 = in_sizes[0] / 2, E1 = in_sizes[1] / 2;
    int E2 = in_sizes[2] / 2, E3 = in_sizes[3] / 2;
    int Emax = max(max(E0, E1), max(E2, E3));
    scatter_all<<<(Emax + 255) / 256, 256, 0, stream>>>(
        (const int*)d_in[0], (const int*)d_in[1], (const int*)d_in[2],
        (const int*)d_in[3], E0, E1, E2, E3, masks);

    build_both<<<4096, 256, 0, stream>>>(masks, E, ET);

    gemm_ep<<<528, 512, 0, stream>>>(E, ET, Pt, P1, Nt, N1, (float*)d_out);
}